// Round 5
// baseline (901.030 us; speedup 1.0000x reference)
//
#include <hip/hip_runtime.h>

#define NTAG 128
#define SEQ 512
#define NBATCH 512
#define END_ID 1
#define GB 16          // batches per group (MFMA N dimension)
#define NW 8           // waves per block: one 16-row j-tile each
#define EMARGIN 4      // renorm headroom bits

typedef _Float16 v8h __attribute__((ext_vector_type(8)));
typedef _Float16 h2v __attribute__((ext_vector_type(2)));
typedef float f32x4 __attribute__((ext_vector_type(4)));
typedef __fp16 fp16x2 __attribute__((ext_vector_type(2)));

#define LOG2E 1.4426950408889634f
#define LN2   0.6931471805599453f

__device__ __forceinline__ uint pack2(float a, float b) {
  fp16x2 h = __builtin_amdgcn_cvt_pkrtz(a, b);
  return __builtin_bit_cast(uint, h);
}
__device__ __forceinline__ float fast_exp2(float x) {
#if __has_builtin(__builtin_amdgcn_exp2f)
  return __builtin_amdgcn_exp2f(x);
#else
  return exp2f(x);
#endif
}
__device__ __forceinline__ float fast_log2(float x) {
#if __has_builtin(__builtin_amdgcn_logf)
  return __builtin_amdgcn_logf(x);
#else
  return log2f(x);
#endif
}
__device__ __forceinline__ v8h vmax8(v8h a, v8h b) {
#if __has_builtin(__builtin_elementwise_max)
  return __builtin_elementwise_max(a, b);
#else
  v8h r;
  #pragma unroll
  for (int i = 0; i < 8; ++i) r[i] = a[i] > b[i] ? a[i] : b[i];
  return r;
#endif
}
__device__ __forceinline__ uint hmax2u(uint a, uint b) {
#if __has_builtin(__builtin_elementwise_max)
  h2v r = __builtin_elementwise_max(__builtin_bit_cast(h2v, a),
                                    __builtin_bit_cast(h2v, b));
  return __builtin_bit_cast(uint, r);
#else
  h2v x = __builtin_bit_cast(h2v, a), y = __builtin_bit_cast(h2v, b);
  h2v r; r[0] = x[0] > y[0] ? x[0] : y[0]; r[1] = x[1] > y[1] ? x[1] : y[1];
  return __builtin_bit_cast(uint, r);
#endif
}

// ROUND-13: round-11's 8-wave j-tile split (validated absmax 0.0) with the
// measured overheads removed:
//   (a) __syncthreads() -> raw `s_waitcnt lgkmcnt(0)` + s_barrier. The
//       __syncthreads vmcnt(0) drain was forcing the in-flight x prefetch to
//       complete EVERY step (~500-900 cyc of HBM latency on the chain; round
//       12 proved prefetch costs nothing when not drained: 38 MB fetch, same
//       time). Raw barrier leaves vmem in flight; compiler waits vmcnt only
//       at use, 4 steps later.
//   (b) oldv (inactive-lane carry) extracted from the already-read q frags
//       via selects -> one fewer ds_read per step.
//   (c) 4 independent MFMA accumulators + pairwise add (chain L+2adds vs 4L).
// 2 waves/SIMD so sibling waves fill each other's MFMA latency (round 12
// showed 1 wave/SIMD leaves ~80% of cycles stalled).
__global__ __launch_bounds__(NW * 64, 1) void crf_kernel(
    const float* __restrict__ x,      // [B,S,T]
    const int*   __restrict__ tags,   // [B,S]
    const float* __restrict__ mask,   // [B,S]
    const float* __restrict__ trans,  // [T,T]
    float* __restrict__ ws)           // [B]
{
  const int bg = blockIdx.x * GB;
  const int tidx = threadIdx.x;
  const int w = tidx >> 6;            // wave = j-tile 0..7
  const int l = tidx & 63;
  const int m = l & 15;               // batch-in-group (B/D column)
  const int h = l >> 4;               // k-group / D row-group
  const int bb = bg + m;

  __shared__ uint4 pbuf[2][4][64];    // [buf][ks][lane] packed B-fragments

  const float* xb   = x    + (size_t)bb * SEQ * NTAG;
  const int*   trow = tags + (size_t)bb * SEQ;

  // ---- len for batch bb ----
  float msum = 0.f;
  {
    const float4* m4 = (const float4*)(mask + (size_t)bb * SEQ);
    #pragma unroll
    for (int k = 0; k < 32; ++k) {
      float4 v = m4[h * 32 + k];
      msum += (v.x + v.y) + (v.z + v.w);
    }
    msum += __shfl_xor(msum, 16);
    msum += __shfl_xor(msum, 32);
  }
  const int len = (int)msum;          // in [1, 509]
  int ml = len;
  #pragma unroll
  for (int off = 1; off < 64; off <<= 1) ml = max(ml, __shfl_xor(ml, off));
  const int maxlen4 = (ml + 3) & ~3;  // multiple of 4 (ring depth; even)

  // ---- A frags for tile w: E'[w*16+m, k] = exp(trans), k-enum kappa =
  //      ks*32 + (e>=4)*16 + h*4 + (e&3)  (same enum as B side; validated) ----
  v8h Af[4];
  {
    const float* rowp = trans + (size_t)(w * 16 + m) * NTAG;
    #pragma unroll
    for (int ks = 0; ks < 4; ++ks) {
      float4 c0 = *(const float4*)(rowp + ks * 32 + h * 4);
      float4 c1 = *(const float4*)(rowp + ks * 32 + 16 + h * 4);
      v8h a;
      a[0] = (_Float16)fast_exp2(c0.x * LOG2E);
      a[1] = (_Float16)fast_exp2(c0.y * LOG2E);
      a[2] = (_Float16)fast_exp2(c0.z * LOG2E);
      a[3] = (_Float16)fast_exp2(c0.w * LOG2E);
      a[4] = (_Float16)fast_exp2(c1.x * LOG2E);
      a[5] = (_Float16)fast_exp2(c1.y * LOG2E);
      a[6] = (_Float16)fast_exp2(c1.z * LOG2E);
      a[7] = (_Float16)fast_exp2(c1.w * LOG2E);
      Af[ks] = a;
    }
  }

  // ---- init P frags (p0 = delta at k=0 -> ks=0, h=0, elem 0) ----
  if (w == 0) {
    #pragma unroll
    for (int ks = 0; ks < 4; ++ks) {
      uint4 z; z.x = 0u; z.y = 0u; z.z = 0u; z.w = 0u;
      if (ks == 0 && h == 0) z.x = 0x00003C00u;   // f16 1.0 in low half
      pbuf[0][ks][l] = z;
    }
  }
  float M = 0.f;

  // ---- x ring (depth 4); lane reads x[bb][t][w*16 + h*4 .. +3] ----
  const float* xj = xb + w * 16 + h * 4;
  float4 xf0 = *(const float4*)(xj + 0 * NTAG);
  float4 xf1 = *(const float4*)(xj + 1 * NTAG);
  float4 xf2 = *(const float4*)(xj + 2 * NTAG);
  float4 xf3 = *(const float4*)(xj + 3 * NTAG);

  asm volatile("s_waitcnt lgkmcnt(0)" ::: "memory");
  __builtin_amdgcn_s_barrier();

  const f32x4 zero4 = {0.f, 0.f, 0.f, 0.f};
  const int wks = w >> 1;             // which ks-buffer holds this wave's slot
  const int whalf = w & 1;            // which uint2 half

#define CRF_STEP(XF, S_)                                                      \
  {                                                                           \
    const int t_  = t + (S_);                                                 \
    const int pp_ = t_ & 1;                                                   \
    const bool act = (t_ < len);                                              \
    const uint4 q0 = pbuf[pp_][0][l];                                         \
    const uint4 q1 = pbuf[pp_][1][l];                                         \
    const uint4 q2 = pbuf[pp_][2][l];                                         \
    const uint4 q3 = pbuf[pp_][3][l];                                         \
    const float4 xv = XF;                                                     \
    XF = *(const float4*)(xj + (size_t)min(t_ + 4, len) * NTAG);              \
    f32x4 d0 = __builtin_amdgcn_mfma_f32_16x16x32_f16(                        \
        Af[0], __builtin_bit_cast(v8h, q0), zero4, 0, 0, 0);                  \
    f32x4 d1 = __builtin_amdgcn_mfma_f32_16x16x32_f16(                        \
        Af[1], __builtin_bit_cast(v8h, q1), zero4, 0, 0, 0);                  \
    f32x4 d2 = __builtin_amdgcn_mfma_f32_16x16x32_f16(                        \
        Af[2], __builtin_bit_cast(v8h, q2), zero4, 0, 0, 0);                  \
    f32x4 d3 = __builtin_amdgcn_mfma_f32_16x16x32_f16(                        \
        Af[3], __builtin_bit_cast(v8h, q3), zero4, 0, 0, 0);                  \
    /* renorm exponent from read frags (independent of MFMA results) */       \
    v8h mt0 = vmax8(__builtin_bit_cast(v8h, q0), __builtin_bit_cast(v8h, q1));\
    v8h mt1 = vmax8(__builtin_bit_cast(v8h, q2), __builtin_bit_cast(v8h, q3));\
    v8h mt2 = vmax8(mt0, mt1);                                                \
    const uint4 tu = __builtin_bit_cast(uint4, mt2);                          \
    uint mu = hmax2u(hmax2u(tu.x, tu.y), hmax2u(tu.z, tu.w));                 \
    mu = hmax2u(mu, (uint)__shfl_xor((int)mu, 16));                           \
    mu = hmax2u(mu, (uint)__shfl_xor((int)mu, 32));                           \
    const h2v mh = __builtin_bit_cast(h2v, mu);                               \
    const float fm = fmaxf((float)mh[0], (float)mh[1]);                       \
    int e_ = ((__float_as_int(fm) >> 23) & 255) - 127;                        \
    e_ = e_ < -30 ? -30 : (e_ > 30 ? 30 : e_);                                \
    const float csh = (float)(e_ + EMARGIN);                                  \
    const f32x4 d = (d0 + d1) + (d2 + d3);                                    \
    const float v0 = d[0] * fast_exp2(fmaf(xv.x, LOG2E, -csh));               \
    const float v1 = d[1] * fast_exp2(fmaf(xv.y, LOG2E, -csh));               \
    const float v2 = d[2] * fast_exp2(fmaf(xv.z, LOG2E, -csh));               \
    const float v3 = d[3] * fast_exp2(fmaf(xv.w, LOG2E, -csh));               \
    /* oldv (inactive carry) from the already-read frags: own slot */         \
    const uint4 qs = wks == 0 ? q0 : wks == 1 ? q1 : wks == 2 ? q2 : q3;      \
    const uint ox = whalf ? qs.z : qs.x;                                      \
    const uint oy = whalf ? qs.w : qs.y;                                      \
    uint2 wr;                                                                 \
    wr.x = act ? pack2(v0, v1) : ox;                                          \
    wr.y = act ? pack2(v2, v3) : oy;                                          \
    ((uint2*)&pbuf[pp_ ^ 1][wks][l])[whalf] = wr;                             \
    M = act ? (M + csh) : M;                                                  \
    asm volatile("s_waitcnt lgkmcnt(0)" ::: "memory");                        \
    __builtin_amdgcn_s_barrier();                                             \
  }

  for (int t = 0; t < maxlen4; t += 4) {
    CRF_STEP(xf0, 0)
    CRF_STEP(xf1, 1)
    CRF_STEP(xf2, 2)
    CRF_STEP(xf3, 3)
  }
#undef CRF_STEP
  // maxlen4 multiple of 4 -> even step count -> final P in pbuf[0]

  if (w == 0) {
    v8h Pk[4];
    #pragma unroll
    for (int ks = 0; ks < 4; ++ks)
      Pk[ks] = __builtin_bit_cast(v8h, pbuf[0][ks][l]);

    // ---- fwd = logsumexp_j(alpha[j] + trans[END][j]); alpha=(M+log2 p)ln2 ----
    const float* tE = trans + (size_t)END_ID * NTAG;
    float vv[4][8];
    float m2 = -3.4e38f;
    #pragma unroll
    for (int ks = 0; ks < 4; ++ks) {
      float4 te0 = *(const float4*)(tE + ks * 32 + h * 4);
      float4 te1 = *(const float4*)(tE + ks * 32 + 16 + h * 4);
      #pragma unroll
      for (int i = 0; i < 8; ++i) {
        const float p  = (float)Pk[ks][i];
        const float te = (i < 4)
            ? ((i & 3) == 0 ? te0.x : (i & 3) == 1 ? te0.y : (i & 3) == 2 ? te0.z : te0.w)
            : ((i & 3) == 0 ? te1.x : (i & 3) == 1 ? te1.y : (i & 3) == 2 ? te1.z : te1.w);
        const float v = (M + fast_log2(p)) * LN2 + te;   // p==0 -> -inf, ok
        vv[ks][i] = v;
        m2 = fmaxf(m2, v);
      }
    }
    m2 = fmaxf(m2, __shfl_xor(m2, 16));
    m2 = fmaxf(m2, __shfl_xor(m2, 32));
    float s = 0.f;
    #pragma unroll
    for (int ks = 0; ks < 4; ++ks)
      #pragma unroll
      for (int i = 0; i < 8; ++i)
        s += fast_exp2((vv[ks][i] - m2) * LOG2E);
    s += __shfl_xor(s, 16);
    s += __shfl_xor(s, 32);
    const float fwd = m2 + fast_log2(s) * LN2;

    // ---- gold score (4 h-lanes per batch, strided) ----
    float g = 0.f;
    for (int i = h; i < len; i += 4) {
      const int tn = trow[i + 1];
      const int tp = trow[i];
      g += xb[(size_t)i * NTAG + tn] + trans[(size_t)tn * NTAG + tp];
    }
    g += __shfl_xor(g, 16);
    g += __shfl_xor(g, 32);

    if (h == 0) {
      const float gold = g + trans[(size_t)END_ID * NTAG + trow[len]];
      ws[bb] = fwd - gold;
    }
  }
}

__global__ void reduce_kernel(const float* __restrict__ ws, float* __restrict__ out) {
  __shared__ float sm[8];
  const int tid = threadIdx.x;   // 512
  float v = ws[tid];
  #pragma unroll
  for (int off = 1; off < 64; off <<= 1) v += __shfl_xor(v, off);
  if ((tid & 63) == 0) sm[tid >> 6] = v;
  __syncthreads();
  if (tid == 0) {
    float s = 0.f;
    #pragma unroll
    for (int w = 0; w < 8; ++w) s += sm[w];
    out[0] = s * (1.0f / 512.0f);
  }
}

extern "C" void kernel_launch(void* const* d_in, const int* in_sizes, int n_in,
                              void* d_out, int out_size, void* d_ws, size_t ws_size,
                              hipStream_t stream) {
  const float* x     = (const float*)d_in[0];
  const int*   tags  = (const int*)d_in[1];
  const float* mask  = (const float*)d_in[2];
  const float* trans = (const float*)d_in[3];
  float*       ws    = (float*)d_ws;

  crf_kernel<<<NBATCH / GB, NW * 64, 0, stream>>>(x, tags, mask, trans, ws);
  reduce_kernel<<<1, 512, 0, stream>>>(ws, (float*)d_out);
}

// Round 6
// 559.226 us; speedup vs baseline: 1.6112x; 1.6112x over previous
//
#include <hip/hip_runtime.h>

#define NTAG 128
#define SEQ 512
#define NBATCH 512
#define END_ID 1
#define NBPW 2          // batches interleaved per wave

typedef _Float16 h2 __attribute__((ext_vector_type(2)));
typedef __fp16 fp16x2 __attribute__((ext_vector_type(2)));
typedef uint u32x32 __attribute__((ext_vector_type(32)));

#define LOG2E 1.4426950408889634f
#define LN2   0.6931471805599453f

__device__ __forceinline__ float bcast0(float v) {
  return __int_as_float(__builtin_amdgcn_readfirstlane(__float_as_int(v)));
}
__device__ __forceinline__ uint pack2(float a, float b) {
  fp16x2 h = __builtin_amdgcn_cvt_pkrtz(a, b);
  return __builtin_bit_cast(uint, h);
}
__device__ __forceinline__ h2 as_h2(uint u) { return __builtin_bit_cast(h2, u); }

__device__ __forceinline__ float fast_exp2(float x) {
#if __has_builtin(__builtin_amdgcn_exp2f)
  return __builtin_amdgcn_exp2f(x);
#else
  return exp2f(x);
#endif
}
__device__ __forceinline__ float fast_log2(float x) {
#if __has_builtin(__builtin_amdgcn_logf)
  return __builtin_amdgcn_logf(x);
#else
  return log2f(x);
#endif
}

#if __has_builtin(__builtin_amdgcn_fdot2)
#define FDOT2(pu, eu, acc) acc = __builtin_amdgcn_fdot2(as_h2(pu), as_h2(eu), acc, false)
#else
#define FDOT2(pu, eu, acc) do { h2 _p = as_h2(pu), _e = as_h2(eu); \
  acc = fmaf((float)_p.x, (float)_e.x, fmaf((float)_p.y, (float)_e.y, acc)); } while (0)
#endif

#define RL(v, l) ((uint)__builtin_amdgcn_readlane((int)(v), (l)))
#define EL(c) ((c) < 32 ? eL0[(c)] : eL1[(c) - 32])
#define EH(c) ((c) < 32 ? eH0[(c)] : eH1[(c) - 32])

// ROUND-14: the round-0 kernel (best measured: 254 us, absmax 0) with TWO
// independent batches interleaved per wave. Evidence from rounds 1-5:
//  - memory latency is NOT on the chain (round 12/4: depth-4 prefetch + half
//    the fetch = zero time change) -> the 1200 cyc/step is VALU ISSUE
//    (~380 inst x 2 cyc wave64) + dep stall;
//  - every cross-wave exchange variant (LDS+barrier, raw s_barrier, in-wave
//    MFMA chain) was slower (315/336/401/409/759 us): sync or MFMA latency
//    lands on the 509-step serial chain.
// Interleaving 2 batches in one wave attacks issue directly: the E'-table
// reads (128/step, batch-INdependent) are shared between the two dot
// streams, and the two chains fill each other's dependency stalls. Grid
// 256 blocks = all 256 CUs active (round 0 used 512 1-wave blocks).
// Per step-pair ~610 inst ~1250 cyc -> ~650-800 cyc/batch-step.
__device__ __forceinline__ float crf_tail(
    float A_lo, float A_hi, int lane, const float* __restrict__ xb,
    const int* __restrict__ trow, int len, const float* __restrict__ trans) {
  const float a_lo = A_lo * LN2;
  const float a_hi = A_hi * LN2;
  const float2 te = ((const float2*)(trans + END_ID * NTAG))[lane];
  const float v_lo = a_lo + te.x;
  const float v_hi = a_hi + te.y;
  float m2 = fmaxf(v_lo, v_hi);
  #pragma unroll
  for (int off = 1; off < 64; off <<= 1) m2 = fmaxf(m2, __shfl_xor(m2, off));
  float s = fast_exp2((v_lo - m2) * LOG2E) + fast_exp2((v_hi - m2) * LOG2E);
  #pragma unroll
  for (int off = 1; off < 64; off <<= 1) s += __shfl_xor(s, off);
  const float fwd = m2 + fast_log2(s) * LN2;

  float g = 0.f;
  for (int i = lane; i < len; i += 64) {
    const int tn = trow[i + 1];
    const int tp = trow[i];
    g += xb[(size_t)i * NTAG + tn] + trans[(size_t)tn * NTAG + tp];
  }
  #pragma unroll
  for (int off = 1; off < 64; off <<= 1) g += __shfl_xor(g, off);
  return fwd - (g + trans[(size_t)END_ID * NTAG + trow[len]]);
}

__global__ __launch_bounds__(64, 1) void crf_kernel(
    const float* __restrict__ x,      // [B,S,T]
    const int*   __restrict__ tags,   // [B,S]
    const float* __restrict__ mask,   // [B,S]
    const float* __restrict__ trans,  // [T,T]
    float* __restrict__ ws)           // [B]
{
  const int b0   = blockIdx.x * NBPW;
  const int b1   = b0 + 1;
  const int lane = threadIdx.x;       // 0..63

  const float* xb0  = x + (size_t)b0 * SEQ * NTAG;
  const float* xb1  = x + (size_t)b1 * SEQ * NTAG;
  const int* trow0  = tags + (size_t)b0 * SEQ;
  const int* trow1  = tags + (size_t)b1 * SEQ;

  // ---- lengths (mask rows are exact 0/1, monotonic) ----
  float ms0 = 0.f, ms1 = 0.f;
  {
    const float* mr0 = mask + (size_t)b0 * SEQ;
    const float* mr1 = mask + (size_t)b1 * SEQ;
    #pragma unroll
    for (int i = 0; i < SEQ / 64; ++i) {
      ms0 += mr0[lane + i * 64];
      ms1 += mr1[lane + i * 64];
    }
    #pragma unroll
    for (int off = 1; off < 64; off <<= 1) {
      ms0 += __shfl_xor(ms0, off);
      ms1 += __shfl_xor(ms1, off);
    }
  }
  const int len0 = (int)ms0;          // in [1, 509]
  const int len1 = (int)ms1;
  const int mlen = max(len0, len1);

  // ---- E' rows 2l (L) and 2l+1 (H): exp2(T*log2e), f16-paired; SHARED
  //      between the two batch streams (batch-independent) ----
  u32x32 eL0, eL1, eH0, eH1;
  {
    const float4* r0 = (const float4*)(trans + (size_t)(2 * lane) * NTAG);
    const float4* r1 = (const float4*)(trans + (size_t)(2 * lane + 1) * NTAG);
    #pragma unroll
    for (int k4 = 0; k4 < 16; ++k4) {
      float4 lo = r0[k4], hi = r1[k4];
      eL0[2 * k4 + 0] = pack2(fast_exp2(lo.x * LOG2E), fast_exp2(lo.y * LOG2E));
      eL0[2 * k4 + 1] = pack2(fast_exp2(lo.z * LOG2E), fast_exp2(lo.w * LOG2E));
      eH0[2 * k4 + 0] = pack2(fast_exp2(hi.x * LOG2E), fast_exp2(hi.y * LOG2E));
      eH0[2 * k4 + 1] = pack2(fast_exp2(hi.z * LOG2E), fast_exp2(hi.w * LOG2E));
    }
    #pragma unroll
    for (int k4 = 16; k4 < 32; ++k4) {
      float4 lo = r0[k4], hi = r1[k4];
      eL1[2 * (k4 - 16) + 0] = pack2(fast_exp2(lo.x * LOG2E), fast_exp2(lo.y * LOG2E));
      eL1[2 * (k4 - 16) + 1] = pack2(fast_exp2(lo.z * LOG2E), fast_exp2(lo.w * LOG2E));
      eH1[2 * (k4 - 16) + 0] = pack2(fast_exp2(hi.x * LOG2E), fast_exp2(hi.y * LOG2E));
      eH1[2 * (k4 - 16) + 1] = pack2(fast_exp2(hi.z * LOG2E), fast_exp2(hi.w * LOG2E));
    }
  }

  // log2-domain alphas
  float A0_lo = (lane == 0) ? 0.f : -14427.f;   // START_ID = 0
  float A0_hi = -14427.f;
  float A1_lo = (lane == 0) ? 0.f : -14427.f;
  float A1_hi = -14427.f;

  const float2* xr0 = (const float2*)xb0;      // row t: xr[t*64 + lane]
  const float2* xr1 = (const float2*)xb1;
  // depth-4 prefetch rings (rows 0..3 always in-bounds: SEQ=512)
  float2 xa0 = xr0[0 * 64 + lane], xb_0 = xr1[0 * 64 + lane];
  float2 xa1 = xr0[1 * 64 + lane], xb_1 = xr1[1 * 64 + lane];
  float2 xa2 = xr0[2 * 64 + lane], xb_2 = xr1[2 * 64 + lane];
  float2 xa3 = xr0[3 * 64 + lane], xb_3 = xr1[3 * 64 + lane];

#define CRF_STEP2(XA, XB, S_)                                                 \
  {                                                                           \
    const int g = t + (S_);                                                   \
    const float M0 = bcast0(A0_lo);                                           \
    const float M1 = bcast0(A1_lo);                                           \
    const uint pk0 = pack2(fminf(fast_exp2(A0_lo - M0), 60000.f),             \
                           fminf(fast_exp2(A0_hi - M0), 60000.f));            \
    const uint pk1 = pack2(fminf(fast_exp2(A1_lo - M1), 60000.f),             \
                           fminf(fast_exp2(A1_hi - M1), 60000.f));            \
    const float2 xt0 = XA;                                                    \
    const float2 xt1 = XB;                                                    \
    XA = xr0[(size_t)min(g + 4, len0) * 64 + lane];                           \
    XB = xr1[(size_t)min(g + 4, len1) * 64 + lane];                           \
    float q0L0 = 0.f, q0L1 = 0.f, q0H0 = 0.f, q0H1 = 0.f;                     \
    float q1L0 = 0.f, q1L1 = 0.f, q1H0 = 0.f, q1H1 = 0.f;                     \
    _Pragma("unroll")                                                         \
    for (int gg = 0; gg < 64; gg += 4) {                                      \
      const uint u0 = RL(pk0, gg + 0), w0 = RL(pk1, gg + 0);                  \
      const uint u1 = RL(pk0, gg + 1), w1 = RL(pk1, gg + 1);                  \
      const uint u2 = RL(pk0, gg + 2), w2 = RL(pk1, gg + 2);                  \
      const uint u3 = RL(pk0, gg + 3), w3 = RL(pk1, gg + 3);                  \
      FDOT2(u0, EL(gg + 0), q0L0); FDOT2(w0, EL(gg + 0), q1L0);               \
      FDOT2(u0, EH(gg + 0), q0H0); FDOT2(w0, EH(gg + 0), q1H0);               \
      FDOT2(u1, EL(gg + 1), q0L1); FDOT2(w1, EL(gg + 1), q1L1);               \
      FDOT2(u1, EH(gg + 1), q0H1); FDOT2(w1, EH(gg + 1), q1H1);               \
      FDOT2(u2, EL(gg + 2), q0L0); FDOT2(w2, EL(gg + 2), q1L0);               \
      FDOT2(u2, EH(gg + 2), q0H0); FDOT2(w2, EH(gg + 2), q1H0);               \
      FDOT2(u3, EL(gg + 3), q0L1); FDOT2(w3, EL(gg + 3), q1L1);               \
      FDOT2(u3, EH(gg + 3), q0H1); FDOT2(w3, EH(gg + 3), q1H1);               \
    }                                                                         \
    const float q0L = q0L0 + q0L1, q0H = q0H0 + q0H1;                         \
    const float q1L = q1L0 + q1L1, q1H = q1H0 + q1H1;                         \
    const float n0L = fmaf(xt0.x, LOG2E, M0 + fast_log2(q0L));                \
    const float n0H = fmaf(xt0.y, LOG2E, M0 + fast_log2(q0H));                \
    const float n1L = fmaf(xt1.x, LOG2E, M1 + fast_log2(q1L));                \
    const float n1H = fmaf(xt1.y, LOG2E, M1 + fast_log2(q1H));                \
    const bool a0 = (g < len0);                                               \
    const bool a1 = (g < len1);                                               \
    A0_lo = a0 ? n0L : A0_lo;  A0_hi = a0 ? n0H : A0_hi;                      \
    A1_lo = a1 ? n1L : A1_lo;  A1_hi = a1 ? n1H : A1_hi;                      \
  }

  for (int t = 0; t < mlen; t += 4) {
    CRF_STEP2(xa0, xb_0, 0)
    CRF_STEP2(xa1, xb_1, 1)
    CRF_STEP2(xa2, xb_2, 2)
    CRF_STEP2(xa3, xb_3, 3)
  }
#undef CRF_STEP2

  // ---- epilogues (independent per batch) ----
  const float r0v = crf_tail(A0_lo, A0_hi, lane, xb0, trow0, len0, trans);
  const float r1v = crf_tail(A1_lo, A1_hi, lane, xb1, trow1, len1, trans);
  if (lane == 0) {
    ws[b0] = r0v;
    ws[b1] = r1v;
  }
}

__global__ void reduce_kernel(const float* __restrict__ ws, float* __restrict__ out) {
  __shared__ float sm[8];
  const int tid = threadIdx.x;   // 512
  float v = ws[tid];
  #pragma unroll
  for (int off = 1; off < 64; off <<= 1) v += __shfl_xor(v, off);
  if ((tid & 63) == 0) sm[tid >> 6] = v;
  __syncthreads();
  if (tid == 0) {
    float s = 0.f;
    #pragma unroll
    for (int w = 0; w < 8; ++w) s += sm[w];
    out[0] = s * (1.0f / 512.0f);
  }
}

extern "C" void kernel_launch(void* const* d_in, const int* in_sizes, int n_in,
                              void* d_out, int out_size, void* d_ws, size_t ws_size,
                              hipStream_t stream) {
  const float* x     = (const float*)d_in[0];
  const int*   tags  = (const int*)d_in[1];
  const float* mask  = (const float*)d_in[2];
  const float* trans = (const float*)d_in[3];
  float*       ws    = (float*)d_ws;

  crf_kernel<<<NBATCH / NBPW, 64, 0, stream>>>(x, tags, mask, trans, ws);
  reduce_kernel<<<1, 512, 0, stream>>>(ws, (float*)d_out);
}